// Round 1
// baseline (604.073 us; speedup 1.0000x reference)
//
#include <hip/hip_runtime.h>

// Problem constants
#define NPG   39
#define NGRAPH 8192
#define EPG   312           // input edges per graph
#define EDG   351           // + 39 self loops
#define E0    2555904       // total input edges (8192*312)
#define FDIM  4560
#define KP    4608          // padded K for bf16 GEMM (multiple of 128)

typedef __bf16 bf16x8 __attribute__((ext_vector_type(8)));
typedef float  f32x4  __attribute__((ext_vector_type(4)));

__device__ __forceinline__ unsigned short f2b(float f) {
  unsigned int u = __float_as_uint(f);
  u += 0x7fffu + ((u >> 16) & 1u);            // RNE to bf16
  return (unsigned short)(u >> 16);
}

// =========================== fused GAT kernel ===========================
// one block (128 threads) per graph; everything in LDS; CSR built once.
#define BT 128

template<int Fi, int Fo>
__device__ void gat_layer_dev(float* hin, float* hout, float* sn, float* dn,
                              float* alpha, const unsigned short* csr_src,
                              const unsigned short* csr_ptr,
                              const float* __restrict__ W, const float* __restrict__ as_,
                              const float* __restrict__ ad_, const float* __restrict__ bias,
                              unsigned short* f_row, int res_off, int out_off, int tid) {
  const int Si = Fi + 1, So = Fo + 1;          // padded LDS strides
  // P1: h = x @ W
  for (int idx = tid; idx < NPG * Fo; idx += BT) {
    int n = idx / Fo, o = idx - n * Fo;
    float acc = 0.f;
#pragma unroll
    for (int i = 0; i < Fi; ++i) acc += hin[n * Si + i] * W[i * Fo + o];
    hout[n * So + o] = acc;
  }
  __syncthreads();
  // P2: per-node attention scalars
  for (int n = tid; n < NPG; n += BT) {
    float sA = 0.f, sB = 0.f;
#pragma unroll
    for (int o = 0; o < Fo; ++o) {
      float h = hout[n * So + o];
      sA += h * as_[o]; sB += h * ad_[o];
    }
    sn[n] = sA; dn[n] = sB;
  }
  __syncthreads();
  // P3: per-dst softmax over incoming edges
  for (int d = tid; d < NPG; d += BT) {
    int rs = csr_ptr[d], re = csr_ptr[d + 1];
    float dv = dn[d];
    float m = -3.4e38f;
    for (int k = rs; k < re; ++k) {
      float e = sn[csr_src[k]] + dv;
      e = (e >= 0.f) ? e : 0.2f * e;           // leaky_relu 0.2
      alpha[k] = e;
      m = fmaxf(m, e);
    }
    float den = 0.f;
    for (int k = rs; k < re; ++k) { float w = __expf(alpha[k] - m); alpha[k] = w; den += w; }
    float inv = 1.f / (den + 1e-16f);
    for (int k = rs; k < re; ++k) alpha[k] *= inv;
  }
  __syncthreads();
  // P4: aggregate + bias + relu; write res features; store next-layer input
  for (int idx = tid; idx < NPG * Fo; idx += BT) {
    int d = idx / Fo, o = idx - d * Fo;
    int rs = csr_ptr[d], re = csr_ptr[d + 1];
    float acc = 0.f;
    for (int k = rs; k < re; ++k) acc += alpha[k] * hout[csr_src[k] * So + o];
    float v = fmaxf(acc + bias[o], 0.f);
    hin[d * So + o] = v;
    f_row[res_off + d * Fo + o] = f2b(v);
  }
  __syncthreads();
  // P5: per-graph max pool (post-relu values, all >= 0)
  for (int o = tid; o < Fo; o += BT) {
    float mx = 0.f;
    for (int n = 0; n < NPG; ++n) mx = fmaxf(mx, hin[n * So + o]);
    f_row[out_off + o] = f2b(mx);
  }
  __syncthreads();
}

__global__ __launch_bounds__(BT) void gat_fused(
    const float* __restrict__ x, const int* __restrict__ ei,
    const float* __restrict__ W1, const float* __restrict__ as1, const float* __restrict__ ad1, const float* __restrict__ b1,
    const float* __restrict__ W2, const float* __restrict__ as2, const float* __restrict__ ad2, const float* __restrict__ b2,
    const float* __restrict__ W3, const float* __restrict__ as3, const float* __restrict__ ad3, const float* __restrict__ b3,
    const float* __restrict__ W4, const float* __restrict__ as4, const float* __restrict__ ad4, const float* __restrict__ b4,
    unsigned short* __restrict__ f) {
  __shared__ float hin[NPG * 65];
  __shared__ float hout[NPG * 65];
  __shared__ float sn[NPG], dn[NPG];
  __shared__ float alpha[EDG];
  __shared__ unsigned short csr_src[EDG];
  __shared__ unsigned short csr_ptr[NPG + 1];
  __shared__ int cnt[NPG];

  const int b = blockIdx.x;
  const int tid = threadIdx.x;
  const int* srcg = ei + (size_t)b * EPG;
  const int* dstg = ei + E0 + (size_t)b * EPG;
  unsigned short* f_row = f + (size_t)b * KP;
  const int base = b * NPG;

  for (int i = tid; i < NPG; i += BT) cnt[i] = 0;
  // load x, write res0, zero the K-pad
  for (int n = tid; n < NPG; n += BT) {
    float v = x[(size_t)base + n];
    hin[n * 2] = v;
    f_row[n] = f2b(v);
  }
  for (int i = tid; i < KP - FDIM; i += BT) f_row[FDIM + i] = 0;  // bf16 zero
  __syncthreads();
  // degree count (312 input edges + 39 self loops)
  for (int e = tid; e < EDG; e += BT) {
    int d;
    if (e < EPG) { d = dstg[e] - base; } else { d = e - EPG; }
    d = min(max(d, 0), NPG - 1);
    atomicAdd(&cnt[d], 1);
  }
  if (tid == 0) {                       // out0 = max over raw x
    float m = -3.4e38f;
    for (int n = 0; n < NPG; ++n) m = fmaxf(m, hin[n * 2]);
    f_row[4446] = f2b(m);
  }
  __syncthreads();
  if (tid == 0) {                       // exclusive prefix sum
    int acc = 0;
    for (int n = 0; n < NPG; ++n) { csr_ptr[n] = (unsigned short)acc; acc += cnt[n]; }
    csr_ptr[NPG] = (unsigned short)acc; // == 351
  }
  __syncthreads();
  for (int i = tid; i < NPG; i += BT) cnt[i] = csr_ptr[i];
  __syncthreads();
  for (int e = tid; e < EDG; e += BT) { // scatter
    int s, d;
    if (e < EPG) { s = srcg[e] - base; d = dstg[e] - base; } else { s = d = e - EPG; }
    s = min(max(s, 0), NPG - 1);
    d = min(max(d, 0), NPG - 1);
    int pos = atomicAdd(&cnt[d], 1);
    pos = min(pos, EDG - 1);
    csr_src[pos] = (unsigned short)s;
  }
  __syncthreads();

  gat_layer_dev<1, 8 >(hin, hout, sn, dn, alpha, csr_src, csr_ptr, W1, as1, ad1, b1, f_row, 39,   4447, tid);
  gat_layer_dev<8, 64>(hin, hout, sn, dn, alpha, csr_src, csr_ptr, W2, as2, ad2, b2, f_row, 351,  4455, tid);
  gat_layer_dev<64,32>(hin, hout, sn, dn, alpha, csr_src, csr_ptr, W3, as3, ad3, b3, f_row, 2847, 4519, tid);
  gat_layer_dev<32, 9>(hin, hout, sn, dn, alpha, csr_src, csr_ptr, W4, as4, ad4, b4, f_row, 4095, 4551, tid);
}

// ================= weight transpose + bf16 cast (per launch) =================
// in: f32 [K][NN] row-major -> out: bf16 [NN][Kpad] row-major, zero-fill k>=K
__global__ __launch_bounds__(256) void tcast(const float* __restrict__ in,
                                             unsigned short* __restrict__ out,
                                             int K, int NN, int Kpad) {
  __shared__ float tile[64 * 65];
  const int k0 = blockIdx.x * 64, n0 = blockIdx.y * 64;
  const int tid = threadIdx.x;
#pragma unroll
  for (int i = 0; i < 16; ++i) {
    int idx = i * 256 + tid;
    int r = idx >> 6, c = idx & 63;
    int k = k0 + r;
    tile[r * 65 + c] = (k < K) ? in[(size_t)k * NN + n0 + c] : 0.f;
  }
  __syncthreads();
#pragma unroll
  for (int i = 0; i < 16; ++i) {
    int idx = i * 256 + tid;
    int r = idx >> 6, c = idx & 63;    // r: n-offset, c: k-offset
    out[(size_t)(n0 + r) * Kpad + k0 + c] = f2b(tile[c * 65 + r]);
  }
}

// =========================== bf16 MFMA GEMM ===========================
// C[M,N] = relu(A[M,K] @ Bt[N,K]^T + bias) ; 128x128 tile, BK=32, 4 waves
template<bool OUT_BF16>
__global__ __launch_bounds__(256) void mfma_gemm(const unsigned short* __restrict__ A,
    const unsigned short* __restrict__ Bt, unsigned short* __restrict__ Cb,
    float* __restrict__ Cf, const float* __restrict__ bias, int K, int N) {
  __shared__ alignas(16) unsigned short As[128 * 32];
  __shared__ alignas(16) unsigned short Bs[128 * 32];
  const int tid = threadIdx.x;
  const int lane = tid & 63;
  const int wave = tid >> 6;
  const int wy = wave >> 1, wx = wave & 1;
  const int m0 = blockIdx.y * 128, n0 = blockIdx.x * 128;

  f32x4 acc[4][4];
  const f32x4 z = {0.f, 0.f, 0.f, 0.f};
#pragma unroll
  for (int i = 0; i < 4; ++i)
#pragma unroll
    for (int j = 0; j < 4; ++j) acc[i][j] = z;

  const int lr = lane >> 2;          // staging: row within 16-row chunk
  const int lc = (lane & 3) * 8;     // staging: bf16 col offset (16B per lane)
  const int q8 = (lane >> 4) * 8;    // fragment k-chunk
  const int rm = lane & 15;

  for (int k0 = 0; k0 < K; k0 += 32) {
    __syncthreads();
#pragma unroll
    for (int t = 0; t < 2; ++t) {
      int r0 = wave * 32 + t * 16;   // wave-uniform
      const unsigned short* ga = A  + (size_t)(m0 + r0 + lr) * K + k0 + lc;
      const unsigned short* gb = Bt + (size_t)(n0 + r0 + lr) * K + k0 + lc;
      __builtin_amdgcn_global_load_lds(
          (const __attribute__((address_space(1))) unsigned int*)(const void*)ga,
          (__attribute__((address_space(3))) unsigned int*)(void*)&As[r0 * 32], 16, 0, 0);
      __builtin_amdgcn_global_load_lds(
          (const __attribute__((address_space(1))) unsigned int*)(const void*)gb,
          (__attribute__((address_space(3))) unsigned int*)(void*)&Bs[r0 * 32], 16, 0, 0);
    }
    __syncthreads();
    bf16x8 af[4], bfr[4];
#pragma unroll
    for (int i = 0; i < 4; ++i) {
      af[i]  = *(const bf16x8*)&As[(wy * 64 + i * 16 + rm) * 32 + q8];
      bfr[i] = *(const bf16x8*)&Bs[(wx * 64 + i * 16 + rm) * 32 + q8];
    }
#pragma unroll
    for (int i = 0; i < 4; ++i)
#pragma unroll
      for (int j = 0; j < 4; ++j)
        acc[i][j] = __builtin_amdgcn_mfma_f32_16x16x32_bf16(af[i], bfr[j], acc[i][j], 0, 0, 0);
  }
  // epilogue: C/D layout col=lane&15, row=(lane>>4)*4+v
  const int q4 = (lane >> 4) * 4;
#pragma unroll
  for (int i = 0; i < 4; ++i) {
#pragma unroll
    for (int j = 0; j < 4; ++j) {
      int row = m0 + wy * 64 + i * 16 + q4;
      int col = n0 + wx * 64 + j * 16 + rm;
      float bv = bias[col];
#pragma unroll
      for (int v = 0; v < 4; ++v) {
        float val = fmaxf(acc[i][j][v] + bv, 0.f);
        if constexpr (OUT_BF16) Cb[(size_t)(row + v) * N + col] = f2b(val);
        else                    Cf[(size_t)(row + v) * N + col] = val;
      }
    }
  }
}

// =========================== final 128->9 layer ===========================
__global__ __launch_bounds__(256) void mlp3(const float* __restrict__ g2,
                                            const float* __restrict__ w3,
                                            const float* __restrict__ b3,
                                            float* __restrict__ out) {
  __shared__ float gs[64 * 130];
  __shared__ float ws3[128 * 9];
  const int r0 = blockIdx.x * 64;
  const int tid = threadIdx.x;
  for (int i = tid; i < 64 * 128; i += 256)
    gs[(i >> 7) * 130 + (i & 127)] = g2[(size_t)r0 * 128 + i];
  for (int i = tid; i < 128 * 9; i += 256) ws3[i] = w3[i];
  __syncthreads();
  for (int idx = tid; idx < 64 * 9; idx += 256) {
    int r = idx / 9, c = idx - r * 9;
    float acc = b3[c];
#pragma unroll 8
    for (int k = 0; k < 128; ++k) acc += gs[r * 130 + k] * ws3[k * 9 + c];
    out[(size_t)(r0 + r) * 9 + c] = acc;
  }
}

// =========================== launch ===========================
extern "C" void kernel_launch(void* const* d_in, const int* in_sizes, int n_in,
                              void* d_out, int out_size, void* d_ws, size_t ws_size,
                              hipStream_t stream) {
  const float* x   = (const float*)d_in[0];
  const int*   ei  = (const int*)d_in[1];
  // d_in[2] batch_ids unused (deterministic layout)
  const float* W1  = (const float*)d_in[3];
  const float* as1 = (const float*)d_in[4];
  const float* ad1 = (const float*)d_in[5];
  const float* b1  = (const float*)d_in[6];
  const float* W2  = (const float*)d_in[7];
  const float* as2 = (const float*)d_in[8];
  const float* ad2 = (const float*)d_in[9];
  const float* b2  = (const float*)d_in[10];
  const float* W3  = (const float*)d_in[11];
  const float* as3 = (const float*)d_in[12];
  const float* ad3 = (const float*)d_in[13];
  const float* b3  = (const float*)d_in[14];
  const float* W4  = (const float*)d_in[15];
  const float* as4 = (const float*)d_in[16];
  const float* ad4 = (const float*)d_in[17];
  const float* b4  = (const float*)d_in[18];
  const float* lw1 = (const float*)d_in[19];
  const float* lb1 = (const float*)d_in[20];
  const float* lw2 = (const float*)d_in[21];
  const float* lb2 = (const float*)d_in[22];
  const float* lw3 = (const float*)d_in[23];
  const float* lb3 = (const float*)d_in[24];
  float* out = (float*)d_out;

  // workspace carve-up (bf16 stored as u16); total ~106.2 MB
  unsigned short* f   = (unsigned short*)d_ws;            // [8192][4608] bf16
  unsigned short* w1t = f   + (size_t)NGRAPH * KP;        // [1024][4608] bf16
  unsigned short* w2t = w1t + (size_t)1024 * KP;          // [128][1024]  bf16
  unsigned short* g1  = w2t + (size_t)128 * 1024;         // [8192][1024] bf16
  float*          g2  = (float*)(g1 + (size_t)NGRAPH * 1024); // [8192][128] f32

  tcast<<<dim3(KP / 64, 1024 / 64), 256, 0, stream>>>(lw1, w1t, FDIM, 1024, KP);
  tcast<<<dim3(1024 / 64, 128 / 64), 256, 0, stream>>>(lw2, w2t, 1024, 128, 1024);

  gat_fused<<<NGRAPH, BT, 0, stream>>>(x, ei,
      W1, as1, ad1, b1, W2, as2, ad2, b2,
      W3, as3, ad3, b3, W4, as4, ad4, b4, f);

  mfma_gemm<true ><<<dim3(1024 / 128, NGRAPH / 128), 256, 0, stream>>>(
      f, w1t, g1, nullptr, lb1, KP, 1024);
  mfma_gemm<false><<<dim3(128 / 128, NGRAPH / 128), 256, 0, stream>>>(
      g1, w2t, nullptr, g2, lb2, 1024, 128);

  mlp3<<<NGRAPH / 64, 256, 0, stream>>>(g2, lw3, lb3, out);
}

// Round 2
// 530.538 us; speedup vs baseline: 1.1386x; 1.1386x over previous
//
#include <hip/hip_runtime.h>

// Problem constants
#define NPG   39
#define NGRAPH 8192
#define EPG   312           // input edges per graph
#define EDG   351           // + 39 self loops
#define E0    2555904       // total input edges (8192*312)
#define FDIM  4560
#define KP    4608          // padded K for bf16 GEMM (multiple of 128)

typedef __bf16 bf16x8 __attribute__((ext_vector_type(8)));
typedef float  f32x4  __attribute__((ext_vector_type(4)));

__device__ __forceinline__ unsigned short f2b(float f) {
  unsigned int u = __float_as_uint(f);
  u += 0x7fffu + ((u >> 16) & 1u);            // RNE to bf16
  return (unsigned short)(u >> 16);
}
__device__ __forceinline__ float hsum4(f32x4 a) { return (a.x + a.y) + (a.z + a.w); }
__device__ __forceinline__ f32x4 vmax4(f32x4 a, f32x4 b) {
  f32x4 r; r.x = fmaxf(a.x, b.x); r.y = fmaxf(a.y, b.y);
  r.z = fmaxf(a.z, b.z); r.w = fmaxf(a.w, b.w); return r;
}

// ==================== weight transpose prep (f32, tiny) ====================
// wt2: [64][8]  <- W2[8][64] ; wt3: [32][64] <- W3[64][32] ;
// wt4: [12][32] <- W4[32][9] zero-padded rows 9..11
__global__ __launch_bounds__(256) void prep_wt(const float* __restrict__ W2,
                                               const float* __restrict__ W3,
                                               const float* __restrict__ W4,
                                               float* __restrict__ wt2,
                                               float* __restrict__ wt3,
                                               float* __restrict__ wt4) {
  const int tid = threadIdx.x;
  for (int i = tid; i < 64 * 8; i += 256)  { int o = i >> 3, k = i & 7;   wt2[i] = W2[k * 64 + o]; }
  for (int i = tid; i < 32 * 64; i += 256) { int o = i >> 6, k = i & 63;  wt3[i] = W3[k * 32 + o]; }
  for (int i = tid; i < 12 * 32; i += 256) { int o = i >> 5, k = i & 31;  wt4[i] = (o < 9) ? W4[k * 9 + o] : 0.f; }
}

// =========================== fused GAT kernel ===========================
#define BT 256

__shared__ alignas(16) float h0[NPG * 64];     // layer input  (stride Si)
__shared__ alignas(16) float h1[NPG * 64];     // layer output (stride So)
__shared__ alignas(16) float alpha[352];       // edge weights; aliased as pool partials
__shared__ alignas(16) float snb[40];          // aliased as int cnt[] during CSR build
__shared__ alignas(16) float dnb[40];
__shared__ alignas(16) float asl[64], adl[64], bl[64];
__shared__ unsigned short csr_src[352];
__shared__ unsigned short csr_ptr[40];

// Fi in {1,8,64,32}; strides Si (input), So (output, mult of 4; h0 next-stride == So)
template<int Fi, int Fo, int Si, int So>
__device__ void gat_layer_dev(const float* __restrict__ Wt,
                              const float* __restrict__ W1raw,
                              const float* __restrict__ as_, const float* __restrict__ ad_,
                              const float* __restrict__ bias,
                              unsigned short* __restrict__ f_row,
                              int res_off, int out_off, int tid) {
  constexpr int OG4 = So / 4;
  // stage attention vectors + bias (zero-padded to 64)
  for (int o = tid; o < 64; o += BT) {
    asl[o] = (o < Fo) ? as_[o] : 0.f;
    adl[o] = (o < Fo) ? ad_[o] : 0.f;
    bl[o]  = (o < Fo) ? bias[o] : 0.f;
  }
  // ---------------- P1: h1 = h0 @ W ----------------
  if constexpr (Fi == 1) {
    for (int idx = tid; idx < NPG * 2; idx += BT) {
      int n = idx >> 1, o = (idx & 1) * 4;
      float v = h0[n];
      f32x4 wv = *(const f32x4*)&W1raw[o];
      f32x4 r = wv * v;
      *(f32x4*)&h1[n * So + o] = r;
    }
  } else {
    constexpr int OG2 = (Fo + 1) / 2;
    for (int idx = tid; idx < 13 * OG2; idx += BT) {
      int c = idx / OG2, g = idx - c * OG2;
      int o = 2 * g, n0 = 3 * c;
      const float* w0 = Wt + o * Fi;
      const float* w1 = w0 + Fi;
      f32x4 a00 = {0,0,0,0}, a01 = {0,0,0,0};
      f32x4 a10 = {0,0,0,0}, a11 = {0,0,0,0};
      f32x4 a20 = {0,0,0,0}, a21 = {0,0,0,0};
#pragma unroll
      for (int i = 0; i < Fi; i += 4) {
        f32x4 wv0 = *(const f32x4*)(w0 + i);
        f32x4 wv1 = *(const f32x4*)(w1 + i);
        f32x4 x0 = *(const f32x4*)&h0[(n0 + 0) * Si + i];
        f32x4 x1 = *(const f32x4*)&h0[(n0 + 1) * Si + i];
        f32x4 x2 = *(const f32x4*)&h0[(n0 + 2) * Si + i];
        a00 += x0 * wv0; a01 += x0 * wv1;
        a10 += x1 * wv0; a11 += x1 * wv1;
        a20 += x2 * wv0; a21 += x2 * wv1;
      }
      float2 r0 = make_float2(hsum4(a00), hsum4(a01));
      float2 r1 = make_float2(hsum4(a10), hsum4(a11));
      float2 r2 = make_float2(hsum4(a20), hsum4(a21));
      *(float2*)&h1[(n0 + 0) * So + o] = r0;
      *(float2*)&h1[(n0 + 1) * So + o] = r1;
      *(float2*)&h1[(n0 + 2) * So + o] = r2;
    }
  }
  __syncthreads();
  // ---------------- P2: per-node attention scalars ----------------
  for (int n = tid; n < NPG; n += BT) {
    f32x4 sA = {0,0,0,0}, sB = {0,0,0,0};
#pragma unroll
    for (int g = 0; g < OG4; ++g) {
      f32x4 hv = *(const f32x4*)&h1[n * So + 4 * g];
      sA += hv * (*(const f32x4*)&asl[4 * g]);
      sB += hv * (*(const f32x4*)&adl[4 * g]);
    }
    snb[n] = hsum4(sA); dnb[n] = hsum4(sB);
  }
  __syncthreads();
  // ---------------- P3: per-dst softmax ----------------
  for (int d = tid; d < NPG; d += BT) {
    int rs = csr_ptr[d], re = csr_ptr[d + 1];
    float dv = dnb[d];
    float m = -3.4e38f;
    for (int k = rs; k < re; ++k) {
      float e = snb[csr_src[k]] + dv;
      e = (e >= 0.f) ? e : 0.2f * e;           // leaky_relu 0.2
      alpha[k] = e;
      m = fmaxf(m, e);
    }
    float den = 0.f;
    for (int k = rs; k < re; ++k) { float w = __expf(alpha[k] - m); alpha[k] = w; den += w; }
    float inv = 1.f / (den + 1e-16f);
    for (int k = rs; k < re; ++k) alpha[k] *= inv;
  }
  __syncthreads();
  // ---------------- P4: aggregate + bias + relu ----------------
  for (int idx = tid; idx < NPG * OG4; idx += BT) {
    int d = idx / OG4, g = idx - d * OG4, o = 4 * g;
    int rs = csr_ptr[d], re = csr_ptr[d + 1];
    f32x4 acc = {0,0,0,0};
    for (int k = rs; k < re; ++k) {
      float a = alpha[k];
      int s = csr_src[k];
      f32x4 hv = *(const f32x4*)&h1[s * So + o];
      acc += hv * a;
    }
    acc += *(const f32x4*)&bl[o];
    f32x4 zero = {0,0,0,0};
    acc = vmax4(acc, zero);
    *(f32x4*)&h0[d * So + o] = acc;            // next layer input (stride So)
#pragma unroll
    for (int j = 0; j < 4; ++j)
      if (o + j < Fo) f_row[res_off + d * Fo + o + j] = f2b(acc[j]);
  }
  __syncthreads();
  // ---------------- P5: per-graph max pool (2-step) ----------------
  float* pp = alpha;                            // alpha dead now; reuse
  for (int idx = tid; idx < 4 * OG4; idx += BT) {
    int ch = idx / OG4, g = idx - ch * OG4, o = 4 * g;
    f32x4 m = {0,0,0,0};
    for (int n = ch; n < NPG; n += 4) m = vmax4(m, *(const f32x4*)&h0[n * So + o]);
    *(f32x4*)&pp[(ch * OG4 + g) * 4] = m;
  }
  __syncthreads();
  for (int idx = tid; idx < OG4; idx += BT) {
    int o = 4 * idx;
    f32x4 m = *(const f32x4*)&pp[idx * 4];
#pragma unroll
    for (int ch = 1; ch < 4; ++ch) m = vmax4(m, *(const f32x4*)&pp[(ch * OG4 + idx) * 4]);
#pragma unroll
    for (int j = 0; j < 4; ++j)
      if (o + j < Fo) f_row[out_off + o + j] = f2b(m[j]);
  }
  __syncthreads();
}

__global__ __launch_bounds__(BT, 6) void gat_fused(
    const float* __restrict__ x, const int* __restrict__ ei,
    const float* __restrict__ W1, const float* __restrict__ as1, const float* __restrict__ ad1, const float* __restrict__ b1,
    const float* __restrict__ as2, const float* __restrict__ ad2, const float* __restrict__ b2,
    const float* __restrict__ as3, const float* __restrict__ ad3, const float* __restrict__ b3,
    const float* __restrict__ as4, const float* __restrict__ ad4, const float* __restrict__ b4,
    const float* __restrict__ wt2, const float* __restrict__ wt3, const float* __restrict__ wt4,
    unsigned short* __restrict__ f) {
  const int b = blockIdx.x;
  const int tid = threadIdx.x;
  const int* srcg = ei + (size_t)b * EPG;
  const int* dstg = ei + E0 + (size_t)b * EPG;
  unsigned short* f_row = f + (size_t)b * KP;
  const int base = b * NPG;
  int* cnt = (int*)snb;                         // alias: cnt only used pre-P2

  for (int i = tid; i < NPG; i += BT) cnt[i] = 0;
  // load x (stride 1), write res0, zero the K-pad
  for (int n = tid; n < NPG; n += BT) {
    float v = x[(size_t)base + n];
    h0[n] = v;
    f_row[n] = f2b(v);
  }
  for (int i = tid; i < KP - FDIM; i += BT) f_row[FDIM + i] = 0;  // bf16 zero
  __syncthreads();
  // degree count (312 input edges + 39 self loops)
  for (int e = tid; e < EDG; e += BT) {
    int d;
    if (e < EPG) { d = dstg[e] - base; } else { d = e - EPG; }
    d = min(max(d, 0), NPG - 1);
    atomicAdd(&cnt[d], 1);
  }
  if (tid == 0) {                       // out0 = max over raw x
    float m = -3.4e38f;
    for (int n = 0; n < NPG; ++n) m = fmaxf(m, h0[n]);
    f_row[4446] = f2b(m);
  }
  __syncthreads();
  if (tid == 0) {                       // exclusive prefix sum
    int acc = 0;
    for (int n = 0; n < NPG; ++n) { csr_ptr[n] = (unsigned short)acc; acc += cnt[n]; }
    csr_ptr[NPG] = (unsigned short)acc; // == 351
  }
  __syncthreads();
  for (int i = tid; i < NPG; i += BT) cnt[i] = csr_ptr[i];
  __syncthreads();
  for (int e = tid; e < EDG; e += BT) { // scatter
    int s, d;
    if (e < EPG) { s = srcg[e] - base; d = dstg[e] - base; } else { s = d = e - EPG; }
    s = min(max(s, 0), NPG - 1);
    d = min(max(d, 0), NPG - 1);
    int pos = atomicAdd(&cnt[d], 1);
    pos = min(pos, EDG - 1);
    csr_src[pos] = (unsigned short)s;
  }
  __syncthreads();

  //                    Fi  Fo  Si  So
  gat_layer_dev<1,  8,  1,  8 >(nullptr, W1, as1, ad1, b1, f_row, 39,   4447, tid);
  gat_layer_dev<8,  64, 8,  64>(wt2, nullptr, as2, ad2, b2, f_row, 351,  4455, tid);
  gat_layer_dev<64, 32, 64, 32>(wt3, nullptr, as3, ad3, b3, f_row, 2847, 4519, tid);
  gat_layer_dev<32, 9,  32, 12>(wt4, nullptr, as4, ad4, b4, f_row, 4095, 4551, tid);
}

// ================= weight transpose + bf16 cast (per launch) =================
__global__ __launch_bounds__(256) void tcast(const float* __restrict__ in,
                                             unsigned short* __restrict__ out,
                                             int K, int NN, int Kpad) {
  __shared__ float tile[64 * 65];
  const int k0 = blockIdx.x * 64, n0 = blockIdx.y * 64;
  const int tid = threadIdx.x;
#pragma unroll
  for (int i = 0; i < 16; ++i) {
    int idx = i * 256 + tid;
    int r = idx >> 6, c = idx & 63;
    int k = k0 + r;
    tile[r * 65 + c] = (k < K) ? in[(size_t)k * NN + n0 + c] : 0.f;
  }
  __syncthreads();
#pragma unroll
  for (int i = 0; i < 16; ++i) {
    int idx = i * 256 + tid;
    int r = idx >> 6, c = idx & 63;    // r: n-offset, c: k-offset
    out[(size_t)(n0 + r) * Kpad + k0 + c] = f2b(tile[c * 65 + r]);
  }
}

// =========================== bf16 MFMA GEMM ===========================
template<bool OUT_BF16>
__global__ __launch_bounds__(256) void mfma_gemm(const unsigned short* __restrict__ A,
    const unsigned short* __restrict__ Bt, unsigned short* __restrict__ Cb,
    float* __restrict__ Cf, const float* __restrict__ bias, int K, int N) {
  __shared__ alignas(16) unsigned short As[128 * 32];
  __shared__ alignas(16) unsigned short Bs[128 * 32];
  const int tid = threadIdx.x;
  const int lane = tid & 63;
  const int wave = tid >> 6;
  const int wy = wave >> 1, wx = wave & 1;
  const int m0 = blockIdx.y * 128, n0 = blockIdx.x * 128;

  f32x4 acc[4][4];
  const f32x4 z = {0.f, 0.f, 0.f, 0.f};
#pragma unroll
  for (int i = 0; i < 4; ++i)
#pragma unroll
    for (int j = 0; j < 4; ++j) acc[i][j] = z;

  const int lr = lane >> 2;
  const int lc = (lane & 3) * 8;
  const int q8 = (lane >> 4) * 8;
  const int rm = lane & 15;

  for (int k0 = 0; k0 < K; k0 += 32) {
    __syncthreads();
#pragma unroll
    for (int t = 0; t < 2; ++t) {
      int r0 = wave * 32 + t * 16;
      const unsigned short* ga = A  + (size_t)(m0 + r0 + lr) * K + k0 + lc;
      const unsigned short* gb = Bt + (size_t)(n0 + r0 + lr) * K + k0 + lc;
      __builtin_amdgcn_global_load_lds(
          (const __attribute__((address_space(1))) unsigned int*)(const void*)ga,
          (__attribute__((address_space(3))) unsigned int*)(void*)&As[r0 * 32], 16, 0, 0);
      __builtin_amdgcn_global_load_lds(
          (const __attribute__((address_space(1))) unsigned int*)(const void*)gb,
          (__attribute__((address_space(3))) unsigned int*)(void*)&Bs[r0 * 32], 16, 0, 0);
    }
    __syncthreads();
    bf16x8 af[4], bfr[4];
#pragma unroll
    for (int i = 0; i < 4; ++i) {
      af[i]  = *(const bf16x8*)&As[(wy * 64 + i * 16 + rm) * 32 + q8];
      bfr[i] = *(const bf16x8*)&Bs[(wx * 64 + i * 16 + rm) * 32 + q8];
    }
#pragma unroll
    for (int i = 0; i < 4; ++i)
#pragma unroll
      for (int j = 0; j < 4; ++j)
        acc[i][j] = __builtin_amdgcn_mfma_f32_16x16x32_bf16(af[i], bfr[j], acc[i][j], 0, 0, 0);
  }
  const int q4 = (lane >> 4) * 4;
#pragma unroll
  for (int i = 0; i < 4; ++i) {
#pragma unroll
    for (int j = 0; j < 4; ++j) {
      int row = m0 + wy * 64 + i * 16 + q4;
      int col = n0 + wx * 64 + j * 16 + rm;
      float bv = bias[col];
#pragma unroll
      for (int v = 0; v < 4; ++v) {
        float val = fmaxf(acc[i][j][v] + bv, 0.f);
        if constexpr (OUT_BF16) Cb[(size_t)(row + v) * N + col] = f2b(val);
        else                    Cf[(size_t)(row + v) * N + col] = val;
      }
    }
  }
}

// =========================== final 128->9 layer ===========================
__global__ __launch_bounds__(256) void mlp3(const float* __restrict__ g2,
                                            const float* __restrict__ w3,
                                            const float* __restrict__ b3,
                                            float* __restrict__ out) {
  __shared__ float gs[64 * 130];
  __shared__ float ws3[128 * 9];
  const int r0 = blockIdx.x * 64;
  const int tid = threadIdx.x;
  for (int i = tid; i < 64 * 128; i += 256)
    gs[(i >> 7) * 130 + (i & 127)] = g2[(size_t)r0 * 128 + i];
  for (int i = tid; i < 128 * 9; i += 256) ws3[i] = w3[i];
  __syncthreads();
  for (int idx = tid; idx < 64 * 9; idx += 256) {
    int r = idx / 9, c = idx - r * 9;
    float acc = b3[c];
#pragma unroll 8
    for (int k = 0; k < 128; ++k) acc += gs[r * 130 + k] * ws3[k * 9 + c];
    out[(size_t)(r0 + r) * 9 + c] = acc;
  }
}

// =========================== launch ===========================
extern "C" void kernel_launch(void* const* d_in, const int* in_sizes, int n_in,
                              void* d_out, int out_size, void* d_ws, size_t ws_size,
                              hipStream_t stream) {
  const float* x   = (const float*)d_in[0];
  const int*   ei  = (const int*)d_in[1];
  const float* W1  = (const float*)d_in[3];
  const float* as1 = (const float*)d_in[4];
  const float* ad1 = (const float*)d_in[5];
  const float* b1  = (const float*)d_in[6];
  const float* W2  = (const float*)d_in[7];
  const float* as2 = (const float*)d_in[8];
  const float* ad2 = (const float*)d_in[9];
  const float* b2  = (const float*)d_in[10];
  const float* W3  = (const float*)d_in[11];
  const float* as3 = (const float*)d_in[12];
  const float* ad3 = (const float*)d_in[13];
  const float* b3  = (const float*)d_in[14];
  const float* W4  = (const float*)d_in[15];
  const float* as4 = (const float*)d_in[16];
  const float* ad4 = (const float*)d_in[17];
  const float* b4  = (const float*)d_in[18];
  const float* lw1 = (const float*)d_in[19];
  const float* lb1 = (const float*)d_in[20];
  const float* lw2 = (const float*)d_in[21];
  const float* lb2 = (const float*)d_in[22];
  const float* lw3 = (const float*)d_in[23];
  const float* lb3 = (const float*)d_in[24];
  float* out = (float*)d_out;

  // workspace carve-up (bf16 stored as u16); total ~106.2 MB
  unsigned short* f   = (unsigned short*)d_ws;            // [8192][4608] bf16
  unsigned short* w1t = f   + (size_t)NGRAPH * KP;        // [1024][4608] bf16
  unsigned short* w2t = w1t + (size_t)1024 * KP;          // [128][1024]  bf16
  unsigned short* g1  = w2t + (size_t)128 * 1024;         // [8192][1024] bf16
  float*          g2  = (float*)(g1 + (size_t)NGRAPH * 1024); // [8192][128] f32
  // transposed GAT weights live at the head of g1's space: consumed by
  // gat_fused BEFORE mfma_gemm1 writes g1 (stream-ordered, so safe)
  float* wt2 = (float*)g1;            // 512 f32
  float* wt3 = wt2 + 64 * 8;          // 2048 f32
  float* wt4 = wt3 + 32 * 64;         // 384 f32

  prep_wt<<<1, 256, 0, stream>>>(W2, W3, W4, wt2, wt3, wt4);
  tcast<<<dim3(KP / 64, 1024 / 64), 256, 0, stream>>>(lw1, w1t, FDIM, 1024, KP);
  tcast<<<dim3(1024 / 64, 128 / 64), 256, 0, stream>>>(lw2, w2t, 1024, 128, 1024);

  gat_fused<<<NGRAPH, BT, 0, stream>>>(x, ei,
      W1, as1, ad1, b1, as2, ad2, b2, as3, ad3, b3, as4, ad4, b4,
      wt2, wt3, wt4, f);

  mfma_gemm<true ><<<dim3(1024 / 128, NGRAPH / 128), 256, 0, stream>>>(
      f, w1t, g1, nullptr, lb1, KP, 1024);
  mfma_gemm<false><<<dim3(128 / 128, NGRAPH / 128), 256, 0, stream>>>(
      g1, w2t, nullptr, g2, lb2, 1024, 128);

  mlp3<<<NGRAPH / 64, 256, 0, stream>>>(g2, lw3, lb3, out);
}